// Round 8
// baseline (194.341 us; speedup 1.0000x reference)
//
#include <hip/hip_runtime.h>
#include <math.h>

#define DIMD 512
#define SEQ 1280
#define NREAL 1279
#define NTEXT 256
#define NIMG 1024
#define IMGW 32
#define NH 8
#define DH 64
#define BH 32
#define BATCH 4
#define VTW 1344            // Vt padded key width (SEQ + 64)
#define PSTR 200            // compact-P LDS row stride (elems)
#define FLTMAX 3.402823466e38f

typedef __attribute__((ext_vector_type(8))) short short8;
typedef __attribute__((ext_vector_type(4))) float f32x4;
typedef __attribute__((ext_vector_type(4))) unsigned short ushort4v;
typedef __attribute__((ext_vector_type(8))) unsigned short ushort8v;

#define MFMA16(a, b, c) __builtin_amdgcn_mfma_f32_16x16x32_bf16((a), (b), (c), 0, 0, 0)

__device__ __forceinline__ unsigned short f2bf(float x) {
    unsigned int u = __builtin_bit_cast(unsigned int, x);
    u += 0x7fffu + ((u >> 16) & 1u);
    return (unsigned short)(u >> 16);
}

__device__ __forceinline__ void gload16(const unsigned short* g, unsigned short* l) {
    __builtin_amdgcn_global_load_lds(
        (const __attribute__((address_space(1))) unsigned int*)g,
        (__attribute__((address_space(3))) unsigned int*)l,
        16, 0, 0);
}

// ---------------- Kernel 0: fused conversions ----------------
__global__ __launch_bounds__(256) void convert_fused(
    const float* __restrict__ x, const float* __restrict__ Wqkv,
    const float* __restrict__ Wout, unsigned short* __restrict__ xb,
    unsigned short* __restrict__ wqkvt, unsigned short* __restrict__ woutt)
{
    __shared__ unsigned short lds[64 * 65];
    const int blk = blockIdx.x;
    const int t = threadIdx.x;

    if (blk < 1280) {
        const size_t tt = (size_t)blk * 256 + t;
        const size_t e0 = tt * 8;
        const int row = (int)(e0 >> 9);
        const int d = (int)(e0 & 511);
        const int b = row / SEQ;
        const int ns = row - b * SEQ;
        ushort8v o;
        if (ns < NREAL) {
            const float4* p = reinterpret_cast<const float4*>(
                x + ((size_t)b * NREAL + ns) * DIMD + d);
            float4 v0 = p[0], v1 = p[1];
            o[0] = f2bf(v0.x); o[1] = f2bf(v0.y); o[2] = f2bf(v0.z); o[3] = f2bf(v0.w);
            o[4] = f2bf(v1.x); o[5] = f2bf(v1.y); o[6] = f2bf(v1.z); o[7] = f2bf(v1.w);
        } else {
            o = ushort8v{0, 0, 0, 0, 0, 0, 0, 0};
        }
        *reinterpret_cast<ushort8v*>(xb + e0) = o;
        return;
    }

    const bool isq = (blk < 1472);
    const int lb = blk - (isq ? 1280 : 1472);
    const float* W = isq ? Wqkv : Wout;
    unsigned short* Wt = isq ? wqkvt : woutt;
    const int N = isq ? 1536 : 512;
    const int k0 = (lb & 7) * 64, n0 = (lb >> 3) * 64;

    #pragma unroll
    for (int i = 0; i < 4; i++) {
        int idx = t + 256 * i;
        int r = idx >> 4, c4 = (idx & 15) * 4;
        float4 v = *reinterpret_cast<const float4*>(W + (size_t)(k0 + r) * N + n0 + c4);
        lds[(c4 + 0) * 65 + r] = f2bf(v.x);
        lds[(c4 + 1) * 65 + r] = f2bf(v.y);
        lds[(c4 + 2) * 65 + r] = f2bf(v.z);
        lds[(c4 + 3) * 65 + r] = f2bf(v.w);
    }
    __syncthreads();
    #pragma unroll
    for (int i = 0; i < 4; i++) {
        int idx = t + 256 * i;
        int n = idx >> 4, k4 = (idx & 15) * 4;
        ushort4v o;
        #pragma unroll
        for (int j = 0; j < 4; j++) o[j] = lds[n * 65 + k4 + j];
        *reinterpret_cast<ushort4v*>(Wt + (size_t)(n0 + n) * 512 + k0 + k4) = o;
    }
}

// ---------------- MFMA GEMM ----------------
template<int TM, int TN, int EPI>
__global__ __launch_bounds__(256) void mfma_gemm(
    const unsigned short* __restrict__ A, const unsigned short* __restrict__ Bt,
    unsigned short* __restrict__ qb, unsigned short* __restrict__ kb,
    unsigned short* __restrict__ vt,
    const float* __restrict__ bias, float* __restrict__ out)
{
    constexpr int MI = TM / 32;
    constexpr int NI = TN / 32;
    __shared__ __align__(16) unsigned short As[TM * 64];
    __shared__ __align__(16) unsigned short Bs[TN * 64];
    const int tid = threadIdx.x;
    const int lane = tid & 63, w = tid >> 6;
    const int wm = w >> 1, wn = w & 1;
    const int g = lane >> 4, col = lane & 15;
    const int m0 = blockIdx.x * TM, n0 = blockIdx.y * TN;
    char* AsB = (char*)&As[0];
    char* BsB = (char*)&Bs[0];

    f32x4 acc[MI][NI] = {};

    for (int ks = 0; ks < 8; ks++) {
        const int k0 = ks * 64;
        #pragma unroll
        for (int j = 0; j < TM / 32; j++) {
            int rbase = w * (TM / 4) + j * 8;
            int r = rbase + (lane >> 3);
            int cs = (lane & 7) ^ (r & 7);
            gload16(A + (size_t)(m0 + r) * 512 + k0 + cs * 8,
                    (unsigned short*)(AsB + rbase * 128));
        }
        #pragma unroll
        for (int j = 0; j < TN / 32; j++) {
            int rbase = w * (TN / 4) + j * 8;
            int r = rbase + (lane >> 3);
            int cs = (lane & 7) ^ (r & 7);
            gload16(Bt + (size_t)(n0 + r) * 512 + k0 + cs * 8,
                    (unsigned short*)(BsB + rbase * 128));
        }
        __syncthreads();

        short8 af[MI][2], bfr[NI][2];
        #pragma unroll
        for (int mi = 0; mi < MI; mi++) {
            int rA = wm * (TM / 2) + mi * 16 + col;
            #pragma unroll
            for (int kk = 0; kk < 2; kk++) {
                int sl = (kk * 4 + g) ^ (rA & 7);
                af[mi][kk] = *reinterpret_cast<const short8*>(AsB + rA * 128 + sl * 16);
            }
        }
        #pragma unroll
        for (int ni = 0; ni < NI; ni++) {
            int rB = wn * (TN / 2) + ni * 16 + col;
            #pragma unroll
            for (int kk = 0; kk < 2; kk++) {
                int sl = (kk * 4 + g) ^ (rB & 7);
                bfr[ni][kk] = *reinterpret_cast<const short8*>(BsB + rB * 128 + sl * 16);
            }
        }
        #pragma unroll
        for (int kk = 0; kk < 2; kk++)
            #pragma unroll
            for (int mi = 0; mi < MI; mi++)
                #pragma unroll
                for (int ni = 0; ni < NI; ni++)
                    acc[mi][ni] = MFMA16(af[mi][kk], bfr[ni][kk], acc[mi][ni]);
        __syncthreads();
    }

    const int b = m0 / SEQ;
    const int nb = m0 - b * SEQ;

    if (EPI == 0) {
        #pragma unroll
        for (int ni = 0; ni < NI; ni++) {
            const int n = n0 + wn * (TN / 2) + ni * 16 + col;
            const int which = n >> 9;
            const int h = (n >> 6) & 7;
            const int dh = n & 63;
            const int bh = b * NH + h;
            #pragma unroll
            for (int mi = 0; mi < MI; mi++) {
                const int ns0 = nb + wm * (TM / 2) + mi * 16 + 4 * g;
                if (which == 2) {
                    ushort4v pk;
                    #pragma unroll
                    for (int rr = 0; rr < 4; rr++) pk[rr] = f2bf(acc[mi][ni][rr]);
                    *reinterpret_cast<ushort4v*>(
                        vt + ((size_t)bh * DH + dh) * VTW + ns0) = pk;
                } else {
                    unsigned short* dst = which ? kb : qb;
                    const float sc = which ? 1.f : 0.125f;
                    #pragma unroll
                    for (int rr = 0; rr < 4; rr++)
                        dst[((size_t)bh * SEQ + ns0 + rr) * DH + dh] =
                            f2bf(acc[mi][ni][rr] * sc);
                }
            }
        }
    } else {
        #pragma unroll
        for (int ni = 0; ni < NI; ni++) {
            const int n = n0 + wn * (TN / 2) + ni * 16 + col;
            const float bv = bias[n];
            #pragma unroll
            for (int mi = 0; mi < MI; mi++) {
                const int ns0 = nb + wm * (TM / 2) + mi * 16 + 4 * g;
                #pragma unroll
                for (int rr = 0; rr < 4; rr++) {
                    int ns = ns0 + rr;
                    if (ns < NREAL)
                        out[((size_t)b * NREAL + ns) * DIMD + n] = acc[mi][ni][rr] + bv;
                }
            }
        }
    }
}

// ---------------- Split-K attention (unchanged from R7) ----------------
__global__ __launch_bounds__(128) void attn_split(
    const unsigned short* __restrict__ qb, const unsigned short* __restrict__ kb,
    const unsigned short* __restrict__ vt, const int* __restrict__ mask,
    unsigned short* __restrict__ ao)
{
    __shared__ __align__(16) unsigned short P[2][16 * PSTR];
    __shared__ float OB[2][16][64];
    __shared__ float OM[2][16];
    __shared__ float OS[2][16];

    const int blk = blockIdx.x;
    const int tid = threadIdx.x;
    const int wid = tid >> 6, lane = tid & 63;
    const int g = lane >> 4, col = lane & 15;
    unsigned short* Pw = &P[wid][0];

    int bh, qbase;
    float m[4] = {-FLTMAX, -FLTMAX, -FLTMAX, -FLTMAX};
    float s[4] = {0.f, 0.f, 0.f, 0.f};
    f32x4 acc[4] = {};

    if (blk < 512) {
        bh = blk >> 4;
        const int t = blk & 15;
        qbase = t * 16;
        const size_t qrow = (size_t)bh * SEQ + qbase + col;
        const short8 qa0 = *reinterpret_cast<const short8*>(qb + qrow * DH + g * 8);
        const short8 qa1 = *reinterpret_cast<const short8*>(qb + qrow * DH + 32 + g * 8);

        const int nkt = (t >= wid) ? ((t - wid) >> 1) + 1 : 0;
        f32x4 st[8];
        #pragma unroll
        for (int i = 0; i < 8; i++) {
            int kt = 2 * i + wid;
            if (i < nkt) {
                size_t krow = (size_t)bh * SEQ + kt * 16 + col;
                short8 kb0 = *reinterpret_cast<const short8*>(kb + krow * DH + g * 8);
                short8 kb1 = *reinterpret_cast<const short8*>(kb + krow * DH + 32 + g * 8);
                f32x4 sv = {0.f, 0.f, 0.f, 0.f};
                sv = MFMA16(qa0, kb0, sv);
                sv = MFMA16(qa1, kb1, sv);
                if (kt == t) {
                    #pragma unroll
                    for (int rr = 0; rr < 4; rr++)
                        if (col > 4 * g + rr) sv[rr] = -FLTMAX;
                }
                st[i] = sv;
            }
        }
        #pragma unroll
        for (int i = 0; i < 8; i++)
            if (i < nkt)
                #pragma unroll
                for (int rr = 0; rr < 4; rr++) m[rr] = fmaxf(m[rr], st[i][rr]);
        #pragma unroll
        for (int rr = 0; rr < 4; rr++) {
            m[rr] = fmaxf(m[rr], __shfl_xor(m[rr], 1));
            m[rr] = fmaxf(m[rr], __shfl_xor(m[rr], 2));
            m[rr] = fmaxf(m[rr], __shfl_xor(m[rr], 4));
            m[rr] = fmaxf(m[rr], __shfl_xor(m[rr], 8));
        }
        #pragma unroll
        for (int i = 0; i < 8; i++)
            if (i < nkt) {
                #pragma unroll
                for (int rr = 0; rr < 4; rr++) {
                    float e = __expf(st[i][rr] - m[rr]);
                    st[i][rr] = e;
                    s[rr] += e;
                }
            }
        #pragma unroll
        for (int rr = 0; rr < 4; rr++) {
            s[rr] += __shfl_xor(s[rr], 1);
            s[rr] += __shfl_xor(s[rr], 2);
            s[rr] += __shfl_xor(s[rr], 4);
            s[rr] += __shfl_xor(s[rr], 8);
        }
        #pragma unroll
        for (int i = 0; i < 8; i++)
            if (i < nkt)
                #pragma unroll
                for (int rr = 0; rr < 4; rr++)
                    Pw[(4 * g + rr) * PSTR + i * 16 + col] = f2bf(st[i][rr]);
        if (nkt & 1) {
            ushort4v z = {0, 0, 0, 0};
            *reinterpret_cast<ushort4v*>(
                &Pw[(lane >> 2) * PSTR + nkt * 16 + (lane & 3) * 4]) = z;
        }
        const int nck = (nkt + 1) >> 1;
        #pragma unroll
        for (int ck = 0; ck < 4; ck++) {
            if (ck < nck) {
                short8 pa = *reinterpret_cast<const short8*>(
                    Pw + col * PSTR + ck * 32 + g * 8);
                const int key_base = ck * 64 + (g >> 1) * 32 + wid * 16 + (g & 1) * 8;
                #pragma unroll
                for (int n0t = 0; n0t < 4; n0t++) {
                    short8 vb = *reinterpret_cast<const short8*>(
                        vt + ((size_t)bh * DH + n0t * 16 + col) * VTW + key_base);
                    acc[n0t] = MFMA16(pa, vb, acc[n0t]);
                }
            }
        }
    } else {
        const int u = blk - 512;
        bh = u >> 6;
        const int tile = u & 63;
        const int r = tile >> 1, c0 = (tile & 1) << 4;
        qbase = NTEXT + r * IMGW + c0;
        const int b0 = bh >> 3;
        const size_t qrow = (size_t)bh * SEQ + qbase + col;
        const short8 qa0 = *reinterpret_cast<const short8*>(qb + qrow * DH + g * 8);
        const short8 qa1 = *reinterpret_cast<const short8*>(qb + qrow * DH + 32 + g * 8);

        f32x4 st[8];
        #pragma unroll
        for (int i = 0; i < 8; i++) {
            int j = (2 * i + wid) * 16 + col;
            size_t krow = (size_t)bh * SEQ + j;
            short8 kb0 = *reinterpret_cast<const short8*>(kb + krow * DH + g * 8);
            short8 kb1 = *reinterpret_cast<const short8*>(kb + krow * DH + 32 + g * 8);
            f32x4 sv = {0.f, 0.f, 0.f, 0.f};
            sv = MFMA16(qa0, kb0, sv);
            sv = MFMA16(qa1, kb1, sv);
            if (mask[b0 * 256 + j] == 0) {
                #pragma unroll
                for (int rr = 0; rr < 4; rr++) sv[rr] = -FLTMAX;
            }
            st[i] = sv;
        }
        f32x4 sw[2][2];
        bool wv[2];
        #pragma unroll
        for (int wi = 0; wi < 2; wi++) {
            const int wg = 2 * wid + wi;
            const int nr = r - 3 + wg;
            wv[wi] = (nr >= 0);
            if (wv[wi]) {
                #pragma unroll
                for (int ct = 0; ct < 2; ct++) {
                    int nc = c0 - 8 + ct * 16 + col;
                    int ncc = min(max(nc, 0), IMGW - 1);
                    size_t krow = (size_t)bh * SEQ + NTEXT + nr * IMGW + ncc;
                    short8 kb0 = *reinterpret_cast<const short8*>(kb + krow * DH + g * 8);
                    short8 kb1 = *reinterpret_cast<const short8*>(kb + krow * DH + 32 + g * 8);
                    f32x4 sv = {0.f, 0.f, 0.f, 0.f};
                    sv = MFMA16(qa0, kb0, sv);
                    sv = MFMA16(qa1, kb1, sv);
                    #pragma unroll
                    for (int rr = 0; rr < 4; rr++) {
                        int q = 4 * g + rr;
                        int dnc = nc - (c0 + q);
                        bool ok = (nc >= 0) && (nc < IMGW) && (dnc >= -3) &&
                                  (dnc <= ((wg == 3) ? 0 : 3));
                        if (!ok) sv[rr] = -FLTMAX;
                    }
                    sw[wi][ct] = sv;
                }
            }
        }
        #pragma unroll
        for (int i = 0; i < 8; i++)
            #pragma unroll
            for (int rr = 0; rr < 4; rr++) m[rr] = fmaxf(m[rr], st[i][rr]);
        #pragma unroll
        for (int wi = 0; wi < 2; wi++)
            if (wv[wi])
                #pragma unroll
                for (int ct = 0; ct < 2; ct++)
                    #pragma unroll
                    for (int rr = 0; rr < 4; rr++) m[rr] = fmaxf(m[rr], sw[wi][ct][rr]);
        #pragma unroll
        for (int rr = 0; rr < 4; rr++) {
            m[rr] = fmaxf(m[rr], __shfl_xor(m[rr], 1));
            m[rr] = fmaxf(m[rr], __shfl_xor(m[rr], 2));
            m[rr] = fmaxf(m[rr], __shfl_xor(m[rr], 4));
            m[rr] = fmaxf(m[rr], __shfl_xor(m[rr], 8));
        }
        #pragma unroll
        for (int i = 0; i < 8; i++)
            #pragma unroll
            for (int rr = 0; rr < 4; rr++) {
                float e = __expf(st[i][rr] - m[rr]);
                st[i][rr] = e;
                s[rr] += e;
            }
        #pragma unroll
        for (int wi = 0; wi < 2; wi++)
            if (wv[wi])
                #pragma unroll
                for (int ct = 0; ct < 2; ct++)
                    #pragma unroll
                    for (int rr = 0; rr < 4; rr++) {
                        float e = __expf(sw[wi][ct][rr] - m[rr]);
                        sw[wi][ct][rr] = e;
                        s[rr] += e;
                    }
        #pragma unroll
        for (int rr = 0; rr < 4; rr++) {
            s[rr] += __shfl_xor(s[rr], 1);
            s[rr] += __shfl_xor(s[rr], 2);
            s[rr] += __shfl_xor(s[rr], 4);
            s[rr] += __shfl_xor(s[rr], 8);
        }
        #pragma unroll
        for (int i = 0; i < 8; i++)
            #pragma unroll
            for (int rr = 0; rr < 4; rr++)
                Pw[(4 * g + rr) * PSTR + i * 16 + col] = f2bf(st[i][rr]);
        #pragma unroll
        for (int wi = 0; wi < 2; wi++)
            if (wv[wi])
                #pragma unroll
                for (int ct = 0; ct < 2; ct++)
                    #pragma unroll
                    for (int rr = 0; rr < 4; rr++)
                        Pw[(4 * g + rr) * PSTR + 128 + wi * 32 + ct * 16 + col] =
                            f2bf(sw[wi][ct][rr]);
        #pragma unroll
        for (int ck = 0; ck < 4; ck++) {
            short8 pa = *reinterpret_cast<const short8*>(
                Pw + col * PSTR + ck * 32 + g * 8);
            const int key_base = ck * 64 + (g >> 1) * 32 + wid * 16 + (g & 1) * 8;
            #pragma unroll
            for (int n0t = 0; n0t < 4; n0t++) {
                short8 vb = *reinterpret_cast<const short8*>(
                    vt + ((size_t)bh * DH + n0t * 16 + col) * VTW + key_base);
                acc[n0t] = MFMA16(pa, vb, acc[n0t]);
            }
        }
        #pragma unroll
        for (int wi = 0; wi < 2; wi++) {
            if (wv[wi]) {
                const int nr = r - 3 + 2 * wid + wi;
                short8 pa = *reinterpret_cast<const short8*>(
                    Pw + col * PSTR + 128 + wi * 32 + g * 8);
                const size_t vkey = (size_t)(NTEXT + nr * IMGW + c0 - 8 + g * 8);
                #pragma unroll
                for (int n0t = 0; n0t < 4; n0t++) {
                    short8 vb = *reinterpret_cast<const short8*>(
                        vt + ((size_t)bh * DH + n0t * 16 + col) * VTW + vkey);
                    acc[n0t] = MFMA16(pa, vb, acc[n0t]);
                }
            }
        }
    }

    #pragma unroll
    for (int rr = 0; rr < 4; rr++) {
        #pragma unroll
        for (int n0t = 0; n0t < 4; n0t++)
            OB[wid][4 * g + rr][n0t * 16 + col] = acc[n0t][rr];
        if (col == 0) {
            OM[wid][4 * g + rr] = m[rr];
            OS[wid][4 * g + rr] = s[rr];
        }
    }
    __syncthreads();

    const int q = tid >> 3, d0 = (tid & 7) * 8;
    const float m0 = OM[0][q], m1 = OM[1][q];
    const float M = fmaxf(m0, m1);
    const float f0 = __expf(m0 - M), f1 = __expf(m1 - M);
    const float inv = 1.f / (OS[0][q] * f0 + OS[1][q] * f1);
    ushort8v o;
    #pragma unroll
    for (int e = 0; e < 8; e++) {
        float v = (OB[0][q][d0 + e] * f0 + OB[1][q][d0 + e] * f1) * inv;
        o[e] = f2bf(v);
    }
    const int b = bh >> 3, h = bh & 7;
    *reinterpret_cast<ushort8v*>(
        ao + ((size_t)b * SEQ + qbase + q) * DIMD + h * DH + d0) = o;
}

extern "C" void kernel_launch(void* const* d_in, const int* in_sizes, int n_in,
                              void* d_out, int out_size, void* d_ws, size_t ws_size,
                              hipStream_t stream) {
    const float* x    = (const float*)d_in[0];
    const int* mask   = (const int*)d_in[1];
    const float* Wqkv = (const float*)d_in[2];
    const float* Wout = (const float*)d_in[3];
    const float* bout = (const float*)d_in[4];
    float* out = (float*)d_out;

    unsigned short* ws = (unsigned short*)d_ws;
    const size_t XB  = (size_t)5120 * 512;
    const size_t WQT = (size_t)1536 * 512;
    const size_t WOT = (size_t)512 * 512;
    const size_t PER = (size_t)BH * SEQ * DH;
    const size_t VTE = (size_t)BH * DH * VTW;
    unsigned short* xb    = ws;
    unsigned short* wqkvt = xb + XB;
    unsigned short* woutt = wqkvt + WQT;
    unsigned short* qb    = woutt + WOT;
    unsigned short* kb    = qb + PER;
    unsigned short* vt    = kb + PER;
    unsigned short* ao    = vt + VTE;

    convert_fused<<<dim3(1536), dim3(256), 0, stream>>>(
        x, Wqkv, Wout, xb, wqkvt, woutt);
    mfma_gemm<64, 128, 0><<<dim3(80, 12), dim3(256), 0, stream>>>(
        xb, wqkvt, qb, kb, vt, nullptr, nullptr);
    // TIMING PROBE (this round only): attn_split is idempotent (fully
    // overwrites ao from qb/kb/vt). Launching 3x adds exactly 2*t_attn to
    // dur_us, giving per-kernel attribution the fill-swamped top-5 can't.
    attn_split<<<dim3(2560), dim3(128), 0, stream>>>(qb, kb, vt, mask, ao);
    attn_split<<<dim3(2560), dim3(128), 0, stream>>>(qb, kb, vt, mask, ao);
    attn_split<<<dim3(2560), dim3(128), 0, stream>>>(qb, kb, vt, mask, ao);
    mfma_gemm<64, 64, 1><<<dim3(80, 8), dim3(256), 0, stream>>>(
        ao, woutt, nullptr, nullptr, nullptr, bout, out);
}

// Round 10
// 127.278 us; speedup vs baseline: 1.5269x; 1.5269x over previous
//
#include <hip/hip_runtime.h>
#include <math.h>

#define DIMD 512
#define SEQ 1280
#define NREAL 1279
#define NTEXT 256
#define NIMG 1024
#define IMGW 32
#define NH 8
#define DH 64
#define BH 32
#define BATCH 4
#define VTW 1344            // Vt padded key width (SEQ + 64)
#define PSTR 200            // compact-P LDS row stride (elems)
#define FLTMAX 3.402823466e38f

typedef __attribute__((ext_vector_type(8))) short short8;
typedef __attribute__((ext_vector_type(4))) float f32x4;
typedef __attribute__((ext_vector_type(4))) unsigned short ushort4v;
typedef __attribute__((ext_vector_type(8))) unsigned short ushort8v;

#define MFMA16(a, b, c) __builtin_amdgcn_mfma_f32_16x16x32_bf16((a), (b), (c), 0, 0, 0)

__device__ __forceinline__ unsigned short f2bf(float x) {
    unsigned int u = __builtin_bit_cast(unsigned int, x);
    u += 0x7fffu + ((u >> 16) & 1u);
    return (unsigned short)(u >> 16);
}

__device__ __forceinline__ void gload16(const unsigned short* g, unsigned short* l) {
    __builtin_amdgcn_global_load_lds(
        (const __attribute__((address_space(1))) unsigned int*)g,
        (__attribute__((address_space(3))) unsigned int*)l,
        16, 0, 0);
}

// ---------------- Kernel 0: fused conversions ----------------
__global__ __launch_bounds__(256) void convert_fused(
    const float* __restrict__ x, const float* __restrict__ Wqkv,
    const float* __restrict__ Wout, unsigned short* __restrict__ xb,
    unsigned short* __restrict__ wqkvt, unsigned short* __restrict__ woutt)
{
    __shared__ unsigned short lds[64 * 65];
    const int blk = blockIdx.x;
    const int t = threadIdx.x;

    if (blk < 1280) {
        const size_t tt = (size_t)blk * 256 + t;
        const size_t e0 = tt * 8;
        const int row = (int)(e0 >> 9);
        const int d = (int)(e0 & 511);
        const int b = row / SEQ;
        const int ns = row - b * SEQ;
        ushort8v o;
        if (ns < NREAL) {
            const float4* p = reinterpret_cast<const float4*>(
                x + ((size_t)b * NREAL + ns) * DIMD + d);
            float4 v0 = p[0], v1 = p[1];
            o[0] = f2bf(v0.x); o[1] = f2bf(v0.y); o[2] = f2bf(v0.z); o[3] = f2bf(v0.w);
            o[4] = f2bf(v1.x); o[5] = f2bf(v1.y); o[6] = f2bf(v1.z); o[7] = f2bf(v1.w);
        } else {
            o = ushort8v{0, 0, 0, 0, 0, 0, 0, 0};
        }
        *reinterpret_cast<ushort8v*>(xb + e0) = o;
        return;
    }

    const bool isq = (blk < 1472);
    const int lb = blk - (isq ? 1280 : 1472);
    const float* W = isq ? Wqkv : Wout;
    unsigned short* Wt = isq ? wqkvt : woutt;
    const int N = isq ? 1536 : 512;
    const int k0 = (lb & 7) * 64, n0 = (lb >> 3) * 64;

    #pragma unroll
    for (int i = 0; i < 4; i++) {
        int idx = t + 256 * i;
        int r = idx >> 4, c4 = (idx & 15) * 4;
        float4 v = *reinterpret_cast<const float4*>(W + (size_t)(k0 + r) * N + n0 + c4);
        lds[(c4 + 0) * 65 + r] = f2bf(v.x);
        lds[(c4 + 1) * 65 + r] = f2bf(v.y);
        lds[(c4 + 2) * 65 + r] = f2bf(v.z);
        lds[(c4 + 3) * 65 + r] = f2bf(v.w);
    }
    __syncthreads();
    #pragma unroll
    for (int i = 0; i < 4; i++) {
        int idx = t + 256 * i;
        int n = idx >> 4, k4 = (idx & 15) * 4;
        ushort4v o;
        #pragma unroll
        for (int j = 0; j < 4; j++) o[j] = lds[n * 65 + k4 + j];
        *reinterpret_cast<ushort4v*>(Wt + (size_t)(n0 + n) * 512 + k0 + k4) = o;
    }
}

// ---------------- MFMA GEMM ----------------
template<int TM, int TN, int EPI>
__global__ __launch_bounds__(256) void mfma_gemm(
    const unsigned short* __restrict__ A, const unsigned short* __restrict__ Bt,
    unsigned short* __restrict__ qb, unsigned short* __restrict__ kb,
    unsigned short* __restrict__ vt,
    const float* __restrict__ bias, float* __restrict__ out)
{
    constexpr int MI = TM / 32;
    constexpr int NI = TN / 32;
    __shared__ __align__(16) unsigned short As[TM * 64];
    __shared__ __align__(16) unsigned short Bs[TN * 64];
    const int tid = threadIdx.x;
    const int lane = tid & 63, w = tid >> 6;
    const int wm = w >> 1, wn = w & 1;
    const int g = lane >> 4, col = lane & 15;
    const int m0 = blockIdx.x * TM, n0 = blockIdx.y * TN;
    char* AsB = (char*)&As[0];
    char* BsB = (char*)&Bs[0];

    f32x4 acc[MI][NI] = {};

    for (int ks = 0; ks < 8; ks++) {
        const int k0 = ks * 64;
        #pragma unroll
        for (int j = 0; j < TM / 32; j++) {
            int rbase = w * (TM / 4) + j * 8;
            int r = rbase + (lane >> 3);
            int cs = (lane & 7) ^ (r & 7);
            gload16(A + (size_t)(m0 + r) * 512 + k0 + cs * 8,
                    (unsigned short*)(AsB + rbase * 128));
        }
        #pragma unroll
        for (int j = 0; j < TN / 32; j++) {
            int rbase = w * (TN / 4) + j * 8;
            int r = rbase + (lane >> 3);
            int cs = (lane & 7) ^ (r & 7);
            gload16(Bt + (size_t)(n0 + r) * 512 + k0 + cs * 8,
                    (unsigned short*)(BsB + rbase * 128));
        }
        __syncthreads();

        short8 af[MI][2], bfr[NI][2];
        #pragma unroll
        for (int mi = 0; mi < MI; mi++) {
            int rA = wm * (TM / 2) + mi * 16 + col;
            #pragma unroll
            for (int kk = 0; kk < 2; kk++) {
                int sl = (kk * 4 + g) ^ (rA & 7);
                af[mi][kk] = *reinterpret_cast<const short8*>(AsB + rA * 128 + sl * 16);
            }
        }
        #pragma unroll
        for (int ni = 0; ni < NI; ni++) {
            int rB = wn * (TN / 2) + ni * 16 + col;
            #pragma unroll
            for (int kk = 0; kk < 2; kk++) {
                int sl = (kk * 4 + g) ^ (rB & 7);
                bfr[ni][kk] = *reinterpret_cast<const short8*>(BsB + rB * 128 + sl * 16);
            }
        }
        #pragma unroll
        for (int kk = 0; kk < 2; kk++)
            #pragma unroll
            for (int mi = 0; mi < MI; mi++)
                #pragma unroll
                for (int ni = 0; ni < NI; ni++)
                    acc[mi][ni] = MFMA16(af[mi][kk], bfr[ni][kk], acc[mi][ni]);
        __syncthreads();
    }

    const int b = m0 / SEQ;
    const int nb = m0 - b * SEQ;

    if (EPI == 0) {
        #pragma unroll
        for (int ni = 0; ni < NI; ni++) {
            const int n = n0 + wn * (TN / 2) + ni * 16 + col;
            const int which = n >> 9;
            const int h = (n >> 6) & 7;
            const int dh = n & 63;
            const int bh = b * NH + h;
            #pragma unroll
            for (int mi = 0; mi < MI; mi++) {
                const int ns0 = nb + wm * (TM / 2) + mi * 16 + 4 * g;
                if (which == 2) {
                    ushort4v pk;
                    #pragma unroll
                    for (int rr = 0; rr < 4; rr++) pk[rr] = f2bf(acc[mi][ni][rr]);
                    *reinterpret_cast<ushort4v*>(
                        vt + ((size_t)bh * DH + dh) * VTW + ns0) = pk;
                } else {
                    unsigned short* dst = which ? kb : qb;
                    const float sc = which ? 1.f : 0.125f;
                    #pragma unroll
                    for (int rr = 0; rr < 4; rr++)
                        dst[((size_t)bh * SEQ + ns0 + rr) * DH + dh] =
                            f2bf(acc[mi][ni][rr] * sc);
                }
            }
        }
    } else {
        #pragma unroll
        for (int ni = 0; ni < NI; ni++) {
            const int n = n0 + wn * (TN / 2) + ni * 16 + col;
            const float bv = bias[n];
            #pragma unroll
            for (int mi = 0; mi < MI; mi++) {
                const int ns0 = nb + wm * (TM / 2) + mi * 16 + 4 * g;
                #pragma unroll
                for (int rr = 0; rr < 4; rr++) {
                    int ns = ns0 + rr;
                    if (ns < NREAL)
                        out[((size_t)b * NREAL + ns) * DIMD + n] = acc[mi][ni][rr] + bv;
                }
            }
        }
    }
}

// ---------------- Split-K attention with XCD-aware swizzle ----------------
// Logical block L = bh*80 + sub; sub<16: text tile t=sub; else img tile=sub-16.
// Physical->logical: L = (phys&7)*320 + (phys>>3)  (bijective, 2560%8==0).
// Each XCD gets 320 contiguous L = 4 bh => ~2.6MB K/V/Q working set, fits 4MB L2.
__global__ __launch_bounds__(128) void attn_split(
    const unsigned short* __restrict__ qb, const unsigned short* __restrict__ kb,
    const unsigned short* __restrict__ vt, const int* __restrict__ mask,
    unsigned short* __restrict__ ao)
{
    __shared__ __align__(16) unsigned short P[2][16 * PSTR];
    __shared__ float OB[2][16][64];
    __shared__ float OM[2][16];
    __shared__ float OS[2][16];

    const int phys = blockIdx.x;
    const int L = (phys & 7) * 320 + (phys >> 3);
    const int tid = threadIdx.x;
    const int wid = tid >> 6, lane = tid & 63;
    const int g = lane >> 4, col = lane & 15;
    unsigned short* Pw = &P[wid][0];

    const int bh = L / 80;
    const int sub = L % 80;
    int qbase;
    float m[4] = {-FLTMAX, -FLTMAX, -FLTMAX, -FLTMAX};
    float s[4] = {0.f, 0.f, 0.f, 0.f};
    f32x4 acc[4] = {};

    if (sub < 16) {
        // ---------------- text tile ----------------
        const int t = sub;
        qbase = t * 16;
        const size_t qrow = (size_t)bh * SEQ + qbase + col;
        const short8 qa0 = *reinterpret_cast<const short8*>(qb + qrow * DH + g * 8);
        const short8 qa1 = *reinterpret_cast<const short8*>(qb + qrow * DH + 32 + g * 8);

        const int nkt = (t >= wid) ? ((t - wid) >> 1) + 1 : 0;
        f32x4 st[8];
        #pragma unroll
        for (int i = 0; i < 8; i++) {
            int kt = 2 * i + wid;
            if (i < nkt) {
                size_t krow = (size_t)bh * SEQ + kt * 16 + col;
                short8 kb0 = *reinterpret_cast<const short8*>(kb + krow * DH + g * 8);
                short8 kb1 = *reinterpret_cast<const short8*>(kb + krow * DH + 32 + g * 8);
                f32x4 sv = {0.f, 0.f, 0.f, 0.f};
                sv = MFMA16(qa0, kb0, sv);
                sv = MFMA16(qa1, kb1, sv);
                if (kt == t) {
                    #pragma unroll
                    for (int rr = 0; rr < 4; rr++)
                        if (col > 4 * g + rr) sv[rr] = -FLTMAX;
                }
                st[i] = sv;
            }
        }
        #pragma unroll
        for (int i = 0; i < 8; i++)
            if (i < nkt)
                #pragma unroll
                for (int rr = 0; rr < 4; rr++) m[rr] = fmaxf(m[rr], st[i][rr]);
        #pragma unroll
        for (int rr = 0; rr < 4; rr++) {
            m[rr] = fmaxf(m[rr], __shfl_xor(m[rr], 1));
            m[rr] = fmaxf(m[rr], __shfl_xor(m[rr], 2));
            m[rr] = fmaxf(m[rr], __shfl_xor(m[rr], 4));
            m[rr] = fmaxf(m[rr], __shfl_xor(m[rr], 8));
        }
        #pragma unroll
        for (int i = 0; i < 8; i++)
            if (i < nkt) {
                #pragma unroll
                for (int rr = 0; rr < 4; rr++) {
                    float e = __expf(st[i][rr] - m[rr]);
                    st[i][rr] = e;
                    s[rr] += e;
                }
            }
        #pragma unroll
        for (int rr = 0; rr < 4; rr++) {
            s[rr] += __shfl_xor(s[rr], 1);
            s[rr] += __shfl_xor(s[rr], 2);
            s[rr] += __shfl_xor(s[rr], 4);
            s[rr] += __shfl_xor(s[rr], 8);
        }
        #pragma unroll
        for (int i = 0; i < 8; i++)
            if (i < nkt)
                #pragma unroll
                for (int rr = 0; rr < 4; rr++)
                    Pw[(4 * g + rr) * PSTR + i * 16 + col] = f2bf(st[i][rr]);
        if (nkt & 1) {
            ushort4v z = {0, 0, 0, 0};
            *reinterpret_cast<ushort4v*>(
                &Pw[(lane >> 2) * PSTR + nkt * 16 + (lane & 3) * 4]) = z;
        }
        const int nck = (nkt + 1) >> 1;
        #pragma unroll
        for (int ck = 0; ck < 4; ck++) {
            if (ck < nck) {
                short8 pa = *reinterpret_cast<const short8*>(
                    Pw + col * PSTR + ck * 32 + g * 8);
                const int key_base = ck * 64 + (g >> 1) * 32 + wid * 16 + (g & 1) * 8;
                #pragma unroll
                for (int n0t = 0; n0t < 4; n0t++) {
                    short8 vb = *reinterpret_cast<const short8*>(
                        vt + ((size_t)bh * DH + n0t * 16 + col) * VTW + key_base);
                    acc[n0t] = MFMA16(pa, vb, acc[n0t]);
                }
            }
        }
    } else {
        // ---------------- img tile ----------------
        const int tile = sub - 16;
        const int r = tile >> 1, c0 = (tile & 1) << 4;
        qbase = NTEXT + r * IMGW + c0;
        const int b0 = bh >> 3;
        const size_t qrow = (size_t)bh * SEQ + qbase + col;
        const short8 qa0 = *reinterpret_cast<const short8*>(qb + qrow * DH + g * 8);
        const short8 qa1 = *reinterpret_cast<const short8*>(qb + qrow * DH + 32 + g * 8);

        f32x4 st[8];
        #pragma unroll
        for (int i = 0; i < 8; i++) {
            int j = (2 * i + wid) * 16 + col;
            size_t krow = (size_t)bh * SEQ + j;
            short8 kb0 = *reinterpret_cast<const short8*>(kb + krow * DH + g * 8);
            short8 kb1 = *reinterpret_cast<const short8*>(kb + krow * DH + 32 + g * 8);
            f32x4 sv = {0.f, 0.f, 0.f, 0.f};
            sv = MFMA16(qa0, kb0, sv);
            sv = MFMA16(qa1, kb1, sv);
            if (mask[b0 * 256 + j] == 0) {
                #pragma unroll
                for (int rr = 0; rr < 4; rr++) sv[rr] = -FLTMAX;
            }
            st[i] = sv;
        }
        f32x4 sw[2][2];
        bool wv[2];
        #pragma unroll
        for (int wi = 0; wi < 2; wi++) {
            const int wg = 2 * wid + wi;
            const int nr = r - 3 + wg;
            wv[wi] = (nr >= 0);
            if (wv[wi]) {
                #pragma unroll
                for (int ct = 0; ct < 2; ct++) {
                    int nc = c0 - 8 + ct * 16 + col;
                    int ncc = min(max(nc, 0), IMGW - 1);
                    size_t krow = (size_t)bh * SEQ + NTEXT + nr * IMGW + ncc;
                    short8 kb0 = *reinterpret_cast<const short8*>(kb + krow * DH + g * 8);
                    short8 kb1 = *reinterpret_cast<const short8*>(kb + krow * DH + 32 + g * 8);
                    f32x4 sv = {0.f, 0.f, 0.f, 0.f};
                    sv = MFMA16(qa0, kb0, sv);
                    sv = MFMA16(qa1, kb1, sv);
                    #pragma unroll
                    for (int rr = 0; rr < 4; rr++) {
                        int q = 4 * g + rr;
                        int dnc = nc - (c0 + q);
                        bool ok = (nc >= 0) && (nc < IMGW) && (dnc >= -3) &&
                                  (dnc <= ((wg == 3) ? 0 : 3));
                        if (!ok) sv[rr] = -FLTMAX;
                    }
                    sw[wi][ct] = sv;
                }
            }
        }
        #pragma unroll
        for (int i = 0; i < 8; i++)
            #pragma unroll
            for (int rr = 0; rr < 4; rr++) m[rr] = fmaxf(m[rr], st[i][rr]);
        #pragma unroll
        for (int wi = 0; wi < 2; wi++)
            if (wv[wi])
                #pragma unroll
                for (int ct = 0; ct < 2; ct++)
                    #pragma unroll
                    for (int rr = 0; rr < 4; rr++) m[rr] = fmaxf(m[rr], sw[wi][ct][rr]);
        #pragma unroll
        for (int rr = 0; rr < 4; rr++) {
            m[rr] = fmaxf(m[rr], __shfl_xor(m[rr], 1));
            m[rr] = fmaxf(m[rr], __shfl_xor(m[rr], 2));
            m[rr] = fmaxf(m[rr], __shfl_xor(m[rr], 4));
            m[rr] = fmaxf(m[rr], __shfl_xor(m[rr], 8));
        }
        #pragma unroll
        for (int i = 0; i < 8; i++)
            #pragma unroll
            for (int rr = 0; rr < 4; rr++) {
                float e = __expf(st[i][rr] - m[rr]);
                st[i][rr] = e;
                s[rr] += e;
            }
        #pragma unroll
        for (int wi = 0; wi < 2; wi++)
            if (wv[wi])
                #pragma unroll
                for (int ct = 0; ct < 2; ct++)
                    #pragma unroll
                    for (int rr = 0; rr < 4; rr++) {
                        float e = __expf(sw[wi][ct][rr] - m[rr]);
                        sw[wi][ct][rr] = e;
                        s[rr] += e;
                    }
        #pragma unroll
        for (int rr = 0; rr < 4; rr++) {
            s[rr] += __shfl_xor(s[rr], 1);
            s[rr] += __shfl_xor(s[rr], 2);
            s[rr] += __shfl_xor(s[rr], 4);
            s[rr] += __shfl_xor(s[rr], 8);
        }
        #pragma unroll
        for (int i = 0; i < 8; i++)
            #pragma unroll
            for (int rr = 0; rr < 4; rr++)
                Pw[(4 * g + rr) * PSTR + i * 16 + col] = f2bf(st[i][rr]);
        #pragma unroll
        for (int wi = 0; wi < 2; wi++)
            if (wv[wi])
                #pragma unroll
                for (int ct = 0; ct < 2; ct++)
                    #pragma unroll
                    for (int rr = 0; rr < 4; rr++)
                        Pw[(4 * g + rr) * PSTR + 128 + wi * 32 + ct * 16 + col] =
                            f2bf(sw[wi][ct][rr]);
        #pragma unroll
        for (int ck = 0; ck < 4; ck++) {
            short8 pa = *reinterpret_cast<const short8*>(
                Pw + col * PSTR + ck * 32 + g * 8);
            const int key_base = ck * 64 + (g >> 1) * 32 + wid * 16 + (g & 1) * 8;
            #pragma unroll
            for (int n0t = 0; n0t < 4; n0t++) {
                short8 vb = *reinterpret_cast<const short8*>(
                    vt + ((size_t)bh * DH + n0t * 16 + col) * VTW + key_base);
                acc[n0t] = MFMA16(pa, vb, acc[n0t]);
            }
        }
        #pragma unroll
        for (int wi = 0; wi < 2; wi++) {
            if (wv[wi]) {
                const int nr = r - 3 + 2 * wid + wi;
                short8 pa = *reinterpret_cast<const short8*>(
                    Pw + col * PSTR + 128 + wi * 32 + g * 8);
                const size_t vkey = (size_t)(NTEXT + nr * IMGW + c0 - 8 + g * 8);
                #pragma unroll
                for (int n0t = 0; n0t < 4; n0t++) {
                    short8 vb = *reinterpret_cast<const short8*>(
                        vt + ((size_t)bh * DH + n0t * 16 + col) * VTW + vkey);
                    acc[n0t] = MFMA16(pa, vb, acc[n0t]);
                }
            }
        }
    }

    #pragma unroll
    for (int rr = 0; rr < 4; rr++) {
        #pragma unroll
        for (int n0t = 0; n0t < 4; n0t++)
            OB[wid][4 * g + rr][n0t * 16 + col] = acc[n0t][rr];
        if (col == 0) {
            OM[wid][4 * g + rr] = m[rr];
            OS[wid][4 * g + rr] = s[rr];
        }
    }
    __syncthreads();

    const int q = tid >> 3, d0 = (tid & 7) * 8;
    const float m0 = OM[0][q], m1 = OM[1][q];
    const float M = fmaxf(m0, m1);
    const float f0 = __expf(m0 - M), f1 = __expf(m1 - M);
    const float inv = 1.f / (OS[0][q] * f0 + OS[1][q] * f1);
    ushort8v o;
    #pragma unroll
    for (int e = 0; e < 8; e++) {
        float v = (OB[0][q][d0 + e] * f0 + OB[1][q][d0 + e] * f1) * inv;
        o[e] = f2bf(v);
    }
    const int b = bh >> 3, h = bh & 7;
    *reinterpret_cast<ushort8v*>(
        ao + ((size_t)b * SEQ + qbase + q) * DIMD + h * DH + d0) = o;
}

extern "C" void kernel_launch(void* const* d_in, const int* in_sizes, int n_in,
                              void* d_out, int out_size, void* d_ws, size_t ws_size,
                              hipStream_t stream) {
    const float* x    = (const float*)d_in[0];
    const int* mask   = (const int*)d_in[1];
    const float* Wqkv = (const float*)d_in[2];
    const float* Wout = (const float*)d_in[3];
    const float* bout = (const float*)d_in[4];
    float* out = (float*)d_out;

    unsigned short* ws = (unsigned short*)d_ws;
    const size_t XB  = (size_t)5120 * 512;
    const size_t WQT = (size_t)1536 * 512;
    const size_t WOT = (size_t)512 * 512;
    const size_t PER = (size_t)BH * SEQ * DH;
    const size_t VTE = (size_t)BH * DH * VTW;
    unsigned short* xb    = ws;
    unsigned short* wqkvt = xb + XB;
    unsigned short* woutt = wqkvt + WQT;
    unsigned short* qb    = woutt + WOT;
    unsigned short* kb    = qb + PER;
    unsigned short* vt    = kb + PER;
    unsigned short* ao    = vt + VTE;

    convert_fused<<<dim3(1536), dim3(256), 0, stream>>>(
        x, Wqkv, Wout, xb, wqkvt, woutt);
    mfma_gemm<64, 128, 0><<<dim3(80, 12), dim3(256), 0, stream>>>(
        xb, wqkvt, qb, kb, vt, nullptr, nullptr);
    attn_split<<<dim3(2560), dim3(128), 0, stream>>>(qb, kb, vt, mask, ao);
    mfma_gemm<64, 64, 1><<<dim3(80, 8), dim3(256), 0, stream>>>(
        ao, woutt, nullptr, nullptr, nullptr, bout, out);
}

// Round 11
// 120.683 us; speedup vs baseline: 1.6103x; 1.0547x over previous
//
#include <hip/hip_runtime.h>
#include <math.h>

#define DIMD 512
#define SEQ 1280
#define NREAL 1279
#define NTEXT 256
#define NIMG 1024
#define IMGW 32
#define NH 8
#define DH 64
#define BH 32
#define BATCH 4
#define NKB 41              // vt key blocks of 32 (40 real + 1 pad)
#define PSTR 200            // compact-P LDS row stride (elems)
#define FLTMAX 3.402823466e38f

typedef __attribute__((ext_vector_type(8))) short short8;
typedef __attribute__((ext_vector_type(4))) float f32x4;
typedef __attribute__((ext_vector_type(4))) unsigned short ushort4v;
typedef __attribute__((ext_vector_type(8))) unsigned short ushort8v;

#define MFMA16(a, b, c) __builtin_amdgcn_mfma_f32_16x16x32_bf16((a), (b), (c), 0, 0, 0)

// vt3 blocked layout: element (bh, key k, dh) at ((bh*NKB + k/32)*DH + dh)*32 + k%32
__device__ __forceinline__ size_t vt3_idx(int bh, int k, int dh) {
    return (((size_t)bh * NKB + (k >> 5)) * DH + dh) * 32 + (k & 31);
}

__device__ __forceinline__ unsigned short f2bf(float x) {
    unsigned int u = __builtin_bit_cast(unsigned int, x);
    u += 0x7fffu + ((u >> 16) & 1u);
    return (unsigned short)(u >> 16);
}

__device__ __forceinline__ void gload16(const unsigned short* g, unsigned short* l) {
    __builtin_amdgcn_global_load_lds(
        (const __attribute__((address_space(1))) unsigned int*)g,
        (__attribute__((address_space(3))) unsigned int*)l,
        16, 0, 0);
}

// ---------------- Kernel 0: fused conversions ----------------
__global__ __launch_bounds__(256) void convert_fused(
    const float* __restrict__ x, const float* __restrict__ Wqkv,
    const float* __restrict__ Wout, unsigned short* __restrict__ xb,
    unsigned short* __restrict__ wqkvt, unsigned short* __restrict__ woutt)
{
    __shared__ unsigned short lds[64 * 65];
    const int blk = blockIdx.x;
    const int t = threadIdx.x;

    if (blk < 1280) {
        const size_t tt = (size_t)blk * 256 + t;
        const size_t e0 = tt * 8;
        const int row = (int)(e0 >> 9);
        const int d = (int)(e0 & 511);
        const int b = row / SEQ;
        const int ns = row - b * SEQ;
        ushort8v o;
        if (ns < NREAL) {
            const float4* p = reinterpret_cast<const float4*>(
                x + ((size_t)b * NREAL + ns) * DIMD + d);
            float4 v0 = p[0], v1 = p[1];
            o[0] = f2bf(v0.x); o[1] = f2bf(v0.y); o[2] = f2bf(v0.z); o[3] = f2bf(v0.w);
            o[4] = f2bf(v1.x); o[5] = f2bf(v1.y); o[6] = f2bf(v1.z); o[7] = f2bf(v1.w);
        } else {
            o = ushort8v{0, 0, 0, 0, 0, 0, 0, 0};
        }
        *reinterpret_cast<ushort8v*>(xb + e0) = o;
        return;
    }

    const bool isq = (blk < 1472);
    const int lb = blk - (isq ? 1280 : 1472);
    const float* W = isq ? Wqkv : Wout;
    unsigned short* Wt = isq ? wqkvt : woutt;
    const int N = isq ? 1536 : 512;
    const int k0 = (lb & 7) * 64, n0 = (lb >> 3) * 64;

    #pragma unroll
    for (int i = 0; i < 4; i++) {
        int idx = t + 256 * i;
        int r = idx >> 4, c4 = (idx & 15) * 4;
        float4 v = *reinterpret_cast<const float4*>(W + (size_t)(k0 + r) * N + n0 + c4);
        lds[(c4 + 0) * 65 + r] = f2bf(v.x);
        lds[(c4 + 1) * 65 + r] = f2bf(v.y);
        lds[(c4 + 2) * 65 + r] = f2bf(v.z);
        lds[(c4 + 3) * 65 + r] = f2bf(v.w);
    }
    __syncthreads();
    #pragma unroll
    for (int i = 0; i < 4; i++) {
        int idx = t + 256 * i;
        int n = idx >> 4, k4 = (idx & 15) * 4;
        ushort4v o;
        #pragma unroll
        for (int j = 0; j < 4; j++) o[j] = lds[n * 65 + k4 + j];
        *reinterpret_cast<ushort4v*>(Wt + (size_t)(n0 + n) * 512 + k0 + k4) = o;
    }
}

// ---------------- MFMA GEMM ----------------
template<int TM, int TN, int EPI>
__global__ __launch_bounds__(256) void mfma_gemm(
    const unsigned short* __restrict__ A, const unsigned short* __restrict__ Bt,
    unsigned short* __restrict__ qb, unsigned short* __restrict__ kb,
    unsigned short* __restrict__ vt,
    const float* __restrict__ bias, float* __restrict__ out)
{
    constexpr int MI = TM / 32;
    constexpr int NI = TN / 32;
    __shared__ __align__(16) unsigned short As[TM * 64];
    __shared__ __align__(16) unsigned short Bs[TN * 64];
    const int tid = threadIdx.x;
    const int lane = tid & 63, w = tid >> 6;
    const int wm = w >> 1, wn = w & 1;
    const int g = lane >> 4, col = lane & 15;
    const int m0 = blockIdx.x * TM, n0 = blockIdx.y * TN;
    char* AsB = (char*)&As[0];
    char* BsB = (char*)&Bs[0];

    f32x4 acc[MI][NI] = {};

    for (int ks = 0; ks < 8; ks++) {
        const int k0 = ks * 64;
        #pragma unroll
        for (int j = 0; j < TM / 32; j++) {
            int rbase = w * (TM / 4) + j * 8;
            int r = rbase + (lane >> 3);
            int cs = (lane & 7) ^ (r & 7);
            gload16(A + (size_t)(m0 + r) * 512 + k0 + cs * 8,
                    (unsigned short*)(AsB + rbase * 128));
        }
        #pragma unroll
        for (int j = 0; j < TN / 32; j++) {
            int rbase = w * (TN / 4) + j * 8;
            int r = rbase + (lane >> 3);
            int cs = (lane & 7) ^ (r & 7);
            gload16(Bt + (size_t)(n0 + r) * 512 + k0 + cs * 8,
                    (unsigned short*)(BsB + rbase * 128));
        }
        __syncthreads();

        short8 af[MI][2], bfr[NI][2];
        #pragma unroll
        for (int mi = 0; mi < MI; mi++) {
            int rA = wm * (TM / 2) + mi * 16 + col;
            #pragma unroll
            for (int kk = 0; kk < 2; kk++) {
                int sl = (kk * 4 + g) ^ (rA & 7);
                af[mi][kk] = *reinterpret_cast<const short8*>(AsB + rA * 128 + sl * 16);
            }
        }
        #pragma unroll
        for (int ni = 0; ni < NI; ni++) {
            int rB = wn * (TN / 2) + ni * 16 + col;
            #pragma unroll
            for (int kk = 0; kk < 2; kk++) {
                int sl = (kk * 4 + g) ^ (rB & 7);
                bfr[ni][kk] = *reinterpret_cast<const short8*>(BsB + rB * 128 + sl * 16);
            }
        }
        #pragma unroll
        for (int kk = 0; kk < 2; kk++)
            #pragma unroll
            for (int mi = 0; mi < MI; mi++)
                #pragma unroll
                for (int ni = 0; ni < NI; ni++)
                    acc[mi][ni] = MFMA16(af[mi][kk], bfr[ni][kk], acc[mi][ni]);
        __syncthreads();
    }

    const int b = m0 / SEQ;
    const int nb = m0 - b * SEQ;

    if (EPI == 0) {
        #pragma unroll
        for (int ni = 0; ni < NI; ni++) {
            const int n = n0 + wn * (TN / 2) + ni * 16 + col;
            const int which = n >> 9;
            const int h = (n >> 6) & 7;
            const int dh = n & 63;
            const int bh = b * NH + h;
            #pragma unroll
            for (int mi = 0; mi < MI; mi++) {
                const int ns0 = nb + wm * (TM / 2) + mi * 16 + 4 * g;
                if (which == 2) {
                    ushort4v pk;
                    #pragma unroll
                    for (int rr = 0; rr < 4; rr++) pk[rr] = f2bf(acc[mi][ni][rr]);
                    // blocked vt3: 4 consecutive keys stay inside one 32-block
                    *reinterpret_cast<ushort4v*>(vt + vt3_idx(bh, ns0, dh)) = pk;
                } else {
                    unsigned short* dst = which ? kb : qb;
                    const float sc = which ? 1.f : 0.125f;
                    #pragma unroll
                    for (int rr = 0; rr < 4; rr++)
                        dst[((size_t)bh * SEQ + ns0 + rr) * DH + dh] =
                            f2bf(acc[mi][ni][rr] * sc);
                }
            }
        }
    } else {
        #pragma unroll
        for (int ni = 0; ni < NI; ni++) {
            const int n = n0 + wn * (TN / 2) + ni * 16 + col;
            const float bv = bias[n];
            #pragma unroll
            for (int mi = 0; mi < MI; mi++) {
                const int ns0 = nb + wm * (TM / 2) + mi * 16 + 4 * g;
                #pragma unroll
                for (int rr = 0; rr < 4; rr++) {
                    int ns = ns0 + rr;
                    if (ns < NREAL)
                        out[((size_t)b * NREAL + ns) * DIMD + n] = acc[mi][ni][rr] + bv;
                }
            }
        }
    }
}

// ---------------- Split-K attention, XCD swizzle + blocked-V PV ----------------
__global__ __launch_bounds__(128) void attn_split(
    const unsigned short* __restrict__ qb, const unsigned short* __restrict__ kb,
    const unsigned short* __restrict__ vt, const int* __restrict__ mask,
    unsigned short* __restrict__ ao)
{
    __shared__ __align__(16) unsigned short P[2][16 * PSTR];
    __shared__ float OB[2][16][64];
    __shared__ float OM[2][16];
    __shared__ float OS[2][16];

    const int phys = blockIdx.x;
    const int L = (phys & 7) * 320 + (phys >> 3);
    const int tid = threadIdx.x;
    const int wid = tid >> 6, lane = tid & 63;
    const int g = lane >> 4, col = lane & 15;
    unsigned short* Pw = &P[wid][0];

    const int bh = L / 80;
    const int sub = L % 80;
    int qbase;
    float m[4] = {-FLTMAX, -FLTMAX, -FLTMAX, -FLTMAX};
    float s[4] = {0.f, 0.f, 0.f, 0.f};
    f32x4 acc[4] = {};

    if (sub < 16) {
        // ---------------- text tile ----------------
        const int t = sub;
        qbase = t * 16;
        const size_t qrow = (size_t)bh * SEQ + qbase + col;
        const short8 qa0 = *reinterpret_cast<const short8*>(qb + qrow * DH + g * 8);
        const short8 qa1 = *reinterpret_cast<const short8*>(qb + qrow * DH + 32 + g * 8);

        const int nkt = (t >= wid) ? ((t - wid) >> 1) + 1 : 0;
        f32x4 st[8];
        #pragma unroll
        for (int i = 0; i < 8; i++) {
            int kt = 2 * i + wid;
            if (i < nkt) {
                size_t krow = (size_t)bh * SEQ + kt * 16 + col;
                short8 kb0 = *reinterpret_cast<const short8*>(kb + krow * DH + g * 8);
                short8 kb1 = *reinterpret_cast<const short8*>(kb + krow * DH + 32 + g * 8);
                f32x4 sv = {0.f, 0.f, 0.f, 0.f};
                sv = MFMA16(qa0, kb0, sv);
                sv = MFMA16(qa1, kb1, sv);
                if (kt == t) {
                    #pragma unroll
                    for (int rr = 0; rr < 4; rr++)
                        if (col > 4 * g + rr) sv[rr] = -FLTMAX;
                }
                st[i] = sv;
            }
        }
        #pragma unroll
        for (int i = 0; i < 8; i++)
            if (i < nkt)
                #pragma unroll
                for (int rr = 0; rr < 4; rr++) m[rr] = fmaxf(m[rr], st[i][rr]);
        #pragma unroll
        for (int rr = 0; rr < 4; rr++) {
            m[rr] = fmaxf(m[rr], __shfl_xor(m[rr], 1));
            m[rr] = fmaxf(m[rr], __shfl_xor(m[rr], 2));
            m[rr] = fmaxf(m[rr], __shfl_xor(m[rr], 4));
            m[rr] = fmaxf(m[rr], __shfl_xor(m[rr], 8));
        }
        #pragma unroll
        for (int i = 0; i < 8; i++)
            if (i < nkt) {
                #pragma unroll
                for (int rr = 0; rr < 4; rr++) {
                    float e = __expf(st[i][rr] - m[rr]);
                    st[i][rr] = e;
                    s[rr] += e;
                }
            }
        #pragma unroll
        for (int rr = 0; rr < 4; rr++) {
            s[rr] += __shfl_xor(s[rr], 1);
            s[rr] += __shfl_xor(s[rr], 2);
            s[rr] += __shfl_xor(s[rr], 4);
            s[rr] += __shfl_xor(s[rr], 8);
        }
        #pragma unroll
        for (int i = 0; i < 8; i++)
            if (i < nkt)
                #pragma unroll
                for (int rr = 0; rr < 4; rr++)
                    Pw[(4 * g + rr) * PSTR + i * 16 + col] = f2bf(st[i][rr]);
        if (nkt & 1) {
            ushort4v z = {0, 0, 0, 0};
            *reinterpret_cast<ushort4v*>(
                &Pw[(lane >> 2) * PSTR + nkt * 16 + (lane & 3) * 4]) = z;
        }
        const int nck = (nkt + 1) >> 1;
        __builtin_amdgcn_s_setprio(1);
        #pragma unroll
        for (int ck = 0; ck < 4; ck++) {
            if (ck < nck) {
                short8 pa = *reinterpret_cast<const short8*>(
                    Pw + col * PSTR + ck * 32 + g * 8);
                const int key_base = ck * 64 + (g >> 1) * 32 + wid * 16 + (g & 1) * 8;
                #pragma unroll
                for (int n0t = 0; n0t < 4; n0t++) {
                    short8 vb = *reinterpret_cast<const short8*>(
                        vt + vt3_idx(bh, key_base, n0t * 16 + col));
                    acc[n0t] = MFMA16(pa, vb, acc[n0t]);
                }
            }
        }
        __builtin_amdgcn_s_setprio(0);
    } else {
        // ---------------- img tile ----------------
        const int tile = sub - 16;
        const int r = tile >> 1, c0 = (tile & 1) << 4;
        qbase = NTEXT + r * IMGW + c0;
        const int b0 = bh >> 3;
        const size_t qrow = (size_t)bh * SEQ + qbase + col;
        const short8 qa0 = *reinterpret_cast<const short8*>(qb + qrow * DH + g * 8);
        const short8 qa1 = *reinterpret_cast<const short8*>(qb + qrow * DH + 32 + g * 8);

        f32x4 st[8];
        #pragma unroll
        for (int i = 0; i < 8; i++) {
            int j = (2 * i + wid) * 16 + col;
            size_t krow = (size_t)bh * SEQ + j;
            short8 kb0 = *reinterpret_cast<const short8*>(kb + krow * DH + g * 8);
            short8 kb1 = *reinterpret_cast<const short8*>(kb + krow * DH + 32 + g * 8);
            f32x4 sv = {0.f, 0.f, 0.f, 0.f};
            sv = MFMA16(qa0, kb0, sv);
            sv = MFMA16(qa1, kb1, sv);
            if (mask[b0 * 256 + j] == 0) {
                #pragma unroll
                for (int rr = 0; rr < 4; rr++) sv[rr] = -FLTMAX;
            }
            st[i] = sv;
        }
        f32x4 sw[2][2];
        bool wv[2];
        #pragma unroll
        for (int wi = 0; wi < 2; wi++) {
            const int wg = 2 * wid + wi;
            const int nr = r - 3 + wg;
            wv[wi] = (nr >= 0);
            if (wv[wi]) {
                #pragma unroll
                for (int ct = 0; ct < 2; ct++) {
                    int nc = c0 - 8 + ct * 16 + col;
                    int ncc = min(max(nc, 0), IMGW - 1);
                    size_t krow = (size_t)bh * SEQ + NTEXT + nr * IMGW + ncc;
                    short8 kb0 = *reinterpret_cast<const short8*>(kb + krow * DH + g * 8);
                    short8 kb1 = *reinterpret_cast<const short8*>(kb + krow * DH + 32 + g * 8);
                    f32x4 sv = {0.f, 0.f, 0.f, 0.f};
                    sv = MFMA16(qa0, kb0, sv);
                    sv = MFMA16(qa1, kb1, sv);
                    #pragma unroll
                    for (int rr = 0; rr < 4; rr++) {
                        int q = 4 * g + rr;
                        int dnc = nc - (c0 + q);
                        bool ok = (nc >= 0) && (nc < IMGW) && (dnc >= -3) &&
                                  (dnc <= ((wg == 3) ? 0 : 3));
                        if (!ok) sv[rr] = -FLTMAX;
                    }
                    sw[wi][ct] = sv;
                }
            }
        }
        #pragma unroll
        for (int i = 0; i < 8; i++)
            #pragma unroll
            for (int rr = 0; rr < 4; rr++) m[rr] = fmaxf(m[rr], st[i][rr]);
        #pragma unroll
        for (int wi = 0; wi < 2; wi++)
            if (wv[wi])
                #pragma unroll
                for (int ct = 0; ct < 2; ct++)
                    #pragma unroll
                    for (int rr = 0; rr < 4; rr++) m[rr] = fmaxf(m[rr], sw[wi][ct][rr]);
        #pragma unroll
        for (int rr = 0; rr < 4; rr++) {
            m[rr] = fmaxf(m[rr], __shfl_xor(m[rr], 1));
            m[rr] = fmaxf(m[rr], __shfl_xor(m[rr], 2));
            m[rr] = fmaxf(m[rr], __shfl_xor(m[rr], 4));
            m[rr] = fmaxf(m[rr], __shfl_xor(m[rr], 8));
        }
        #pragma unroll
        for (int i = 0; i < 8; i++)
            #pragma unroll
            for (int rr = 0; rr < 4; rr++) {
                float e = __expf(st[i][rr] - m[rr]);
                st[i][rr] = e;
                s[rr] += e;
            }
        #pragma unroll
        for (int wi = 0; wi < 2; wi++)
            if (wv[wi])
                #pragma unroll
                for (int ct = 0; ct < 2; ct++)
                    #pragma unroll
                    for (int rr = 0; rr < 4; rr++) {
                        float e = __expf(sw[wi][ct][rr] - m[rr]);
                        sw[wi][ct][rr] = e;
                        s[rr] += e;
                    }
        #pragma unroll
        for (int rr = 0; rr < 4; rr++) {
            s[rr] += __shfl_xor(s[rr], 1);
            s[rr] += __shfl_xor(s[rr], 2);
            s[rr] += __shfl_xor(s[rr], 4);
            s[rr] += __shfl_xor(s[rr], 8);
        }
        #pragma unroll
        for (int i = 0; i < 8; i++)
            #pragma unroll
            for (int rr = 0; rr < 4; rr++)
                Pw[(4 * g + rr) * PSTR + i * 16 + col] = f2bf(st[i][rr]);
        #pragma unroll
        for (int wi = 0; wi < 2; wi++)
            if (wv[wi])
                #pragma unroll
                for (int ct = 0; ct < 2; ct++)
                    #pragma unroll
                    for (int rr = 0; rr < 4; rr++)
                        Pw[(4 * g + rr) * PSTR + 128 + wi * 32 + ct * 16 + col] =
                            f2bf(sw[wi][ct][rr]);
        __builtin_amdgcn_s_setprio(1);
        #pragma unroll
        for (int ck = 0; ck < 4; ck++) {
            short8 pa = *reinterpret_cast<const short8*>(
                Pw + col * PSTR + ck * 32 + g * 8);
            const int key_base = ck * 64 + (g >> 1) * 32 + wid * 16 + (g & 1) * 8;
            #pragma unroll
            for (int n0t = 0; n0t < 4; n0t++) {
                short8 vb = *reinterpret_cast<const short8*>(
                    vt + vt3_idx(bh, key_base, n0t * 16 + col));
                acc[n0t] = MFMA16(pa, vb, acc[n0t]);
            }
        }
        #pragma unroll
        for (int wi = 0; wi < 2; wi++) {
            if (wv[wi]) {
                const int nr = r - 3 + 2 * wid + wi;
                short8 pa = *reinterpret_cast<const short8*>(
                    Pw + col * PSTR + 128 + wi * 32 + g * 8);
                const int k = NTEXT + nr * IMGW + c0 - 8 + g * 8;  // 8-aligned run
                #pragma unroll
                for (int n0t = 0; n0t < 4; n0t++) {
                    short8 vb = *reinterpret_cast<const short8*>(
                        vt + vt3_idx(bh, k, n0t * 16 + col));
                    acc[n0t] = MFMA16(pa, vb, acc[n0t]);
                }
            }
        }
        __builtin_amdgcn_s_setprio(0);
    }

    #pragma unroll
    for (int rr = 0; rr < 4; rr++) {
        #pragma unroll
        for (int n0t = 0; n0t < 4; n0t++)
            OB[wid][4 * g + rr][n0t * 16 + col] = acc[n0t][rr];
        if (col == 0) {
            OM[wid][4 * g + rr] = m[rr];
            OS[wid][4 * g + rr] = s[rr];
        }
    }
    __syncthreads();

    const int q = tid >> 3, d0 = (tid & 7) * 8;
    const float m0 = OM[0][q], m1 = OM[1][q];
    const float M = fmaxf(m0, m1);
    const float f0 = __expf(m0 - M), f1 = __expf(m1 - M);
    const float inv = 1.f / (OS[0][q] * f0 + OS[1][q] * f1);
    ushort8v o;
    #pragma unroll
    for (int e = 0; e < 8; e++) {
        float v = (OB[0][q][d0 + e] * f0 + OB[1][q][d0 + e] * f1) * inv;
        o[e] = f2bf(v);
    }
    const int b = bh >> 3, h = bh & 7;
    *reinterpret_cast<ushort8v*>(
        ao + ((size_t)b * SEQ + qbase + q) * DIMD + h * DH + d0) = o;
}

extern "C" void kernel_launch(void* const* d_in, const int* in_sizes, int n_in,
                              void* d_out, int out_size, void* d_ws, size_t ws_size,
                              hipStream_t stream) {
    const float* x    = (const float*)d_in[0];
    const int* mask   = (const int*)d_in[1];
    const float* Wqkv = (const float*)d_in[2];
    const float* Wout = (const float*)d_in[3];
    const float* bout = (const float*)d_in[4];
    float* out = (float*)d_out;

    unsigned short* ws = (unsigned short*)d_ws;
    const size_t XB  = (size_t)5120 * 512;
    const size_t WQT = (size_t)1536 * 512;
    const size_t WOT = (size_t)512 * 512;
    const size_t PER = (size_t)BH * SEQ * DH;
    const size_t VTE = (size_t)BH * NKB * DH * 32;
    unsigned short* xb    = ws;
    unsigned short* wqkvt = xb + XB;
    unsigned short* woutt = wqkvt + WQT;
    unsigned short* qb    = woutt + WOT;
    unsigned short* kb    = qb + PER;
    unsigned short* vt    = kb + PER;
    unsigned short* ao    = vt + VTE;

    convert_fused<<<dim3(1536), dim3(256), 0, stream>>>(
        x, Wqkv, Wout, xb, wqkvt, woutt);
    mfma_gemm<64, 128, 0><<<dim3(80, 12), dim3(256), 0, stream>>>(
        xb, wqkvt, qb, kb, vt, nullptr, nullptr);
    attn_split<<<dim3(2560), dim3(128), 0, stream>>>(qb, kb, vt, mask, ao);
    mfma_gemm<64, 64, 1><<<dim3(80, 8), dim3(256), 0, stream>>>(
        ao, woutt, nullptr, nullptr, nullptr, bout, out);
}